// Round 1
// baseline (443.983 us; speedup 1.0000x reference)
//
#include <hip/hip_runtime.h>
#include <hip/hip_bf16.h>

#define N1 8192
#define N2 8192
#define CDIM 128
#define HC 60
#define WC 80
#define HIMG 480
#define WIMG 640
#define INV_DENOM (1.0f / (8192.0f * 256.0f))

using bf16x8 = __attribute__((ext_vector_type(8))) short;
using f32x4  = __attribute__((ext_vector_type(4))) float;

__device__ __forceinline__ ushort f2bf(float f) {
    union { float f; unsigned u; } x; x.f = f;
    unsigned u = x.u;
    unsigned r = (u + 0x7FFFu + ((u >> 16) & 1u)) >> 16;
    return (ushort)r;
}
__device__ __forceinline__ float bf2f(unsigned bits) {
    union { unsigned u; float f; } x; x.u = bits << 16; return x.f;
}

// ---------- fp32 -> bf16 convert (vectorized) ----------
__global__ void cvt_kernel(const float* __restrict__ in, ushort* __restrict__ out, int n4) {
    int i = blockIdx.x * blockDim.x + threadIdx.x;
    if (i < n4) {
        float4 v = ((const float4*)in)[i];
        ushort4 o;
        o.x = f2bf(v.x); o.y = f2bf(v.y); o.z = f2bf(v.z); o.w = f2bf(v.w);
        ((ushort4*)out)[i] = o;
    }
}

// ---------- positive term ----------
__global__ void pos_kernel(const float* __restrict__ wkp1,
                           const float* __restrict__ kp1d,
                           const float* __restrict__ desc2,
                           float* __restrict__ out) {
    const int i = blockIdx.x;
    const int c = threadIdx.x;            // 128 threads = 2 waves
    float y = wkp1[2 * i], x = wkp1[2 * i + 1];
    float py = fminf(fmaxf(y / (float)(HIMG - 1) * (float)(HC - 1), 0.0f), (float)(HC - 1));
    float px = fminf(fmaxf(x / (float)(WIMG - 1) * (float)(WC - 1), 0.0f), (float)(WC - 1));
    int y0 = min(max((int)floorf(py), 0), HC - 2);
    int x0 = min(max((int)floorf(px), 0), WC - 2);
    float wy = py - (float)y0;
    float wx = px - (float)x0;
    const float* d = desc2 + (size_t)c * (HC * WC) + y0 * WC + x0;
    float v00 = d[0], v01 = d[1], v10 = d[WC], v11 = d[WC + 1];
    float v = v00 * (1.0f - wy) * (1.0f - wx) + v01 * (1.0f - wy) * wx
            + v10 * wy * (1.0f - wx) + v11 * wy * wx;
    float a = kp1d[(size_t)i * CDIM + c];
    float s2 = v * v, sav = a * v;
    #pragma unroll
    for (int off = 32; off >= 1; off >>= 1) {
        s2  += __shfl_down(s2, off);
        sav += __shfl_down(sav, off);
    }
    __shared__ float p2[2], pav[2];
    int wave = threadIdx.x >> 6, lane = threadIdx.x & 63;
    if (lane == 0) { p2[wave] = s2; pav[wave] = sav; }
    __syncthreads();
    if (threadIdx.x == 0) {
        float nrm = sqrtf(p2[0] + p2[1]);
        float pd = (pav[0] + pav[1]) / fmaxf(nrm, 1e-12f);
        float l = fmaxf(1.0f - pd, 0.0f) * (256.0f / 3.0f);
        atomicAdd(out, l * INV_DENOM);
    }
}

// ---------- masked GEMM -> bf16 dots ----------
// A: [N1, 128] bf16 (kp1_desc), B: [N2, 128] bf16 (kp2_desc, acts as B^T)
// dots[i - m_off][j] = dot(A[i], B[j]) - 5 * (||wkp1[i] - kp2[j]|| <= thr)
__global__ __launch_bounds__(256, 2)
void gemm_kernel(const ushort* __restrict__ A, const ushort* __restrict__ B,
                 const float* __restrict__ wkp1, const float* __restrict__ kp2,
                 ushort* __restrict__ dots, int m_off) {
    const int n0 = blockIdx.x * 128;
    const int m0 = m_off + blockIdx.y * 128;
    const int lane = threadIdx.x & 63;
    const int wave = threadIdx.x >> 6;
    const int wm = wave >> 1, wn = wave & 1;
    const int lrow = lane & 15, quad = lane >> 4;

    f32x4 acc[4][4];
    #pragma unroll
    for (int i = 0; i < 4; i++)
        #pragma unroll
        for (int j = 0; j < 4; j++) acc[i][j] = (f32x4){0.f, 0.f, 0.f, 0.f};

    const int mbase = m0 + wm * 64 + lrow;
    const int nbase = n0 + wn * 64 + lrow;
    #pragma unroll
    for (int kit = 0; kit < 4; kit++) {
        const int kk = kit * 32 + quad * 8;
        bf16x8 af[4], bfr[4];
        #pragma unroll
        for (int t = 0; t < 4; t++) {
            af[t]  = *(const bf16x8*)(A + (size_t)(mbase + t * 16) * CDIM + kk);
            bfr[t] = *(const bf16x8*)(B + (size_t)(nbase + t * 16) * CDIM + kk);
        }
        #pragma unroll
        for (int mt = 0; mt < 4; mt++)
            #pragma unroll
            for (int nt = 0; nt < 4; nt++)
                acc[mt][nt] = __builtin_amdgcn_mfma_f32_16x16x32_bf16(
                    af[mt], bfr[nt], acc[mt][nt], 0, 0, 0);
    }

    const float thr = 2.0f * sqrtf(32.0f) + 0.1f;
    const float thr2 = thr * thr;
    #pragma unroll
    for (int nt = 0; nt < 4; nt++) {
        int j = n0 + wn * 64 + nt * 16 + lrow;       // C/D: col = lane&15
        float ky = kp2[2 * j], kx = kp2[2 * j + 1];
        #pragma unroll
        for (int mt = 0; mt < 4; mt++) {
            #pragma unroll
            for (int r = 0; r < 4; r++) {
                int i = m0 + wm * 64 + mt * 16 + quad * 4 + r;  // row = (lane>>4)*4 + reg
                float wy = wkp1[2 * i], wx = wkp1[2 * i + 1];
                float dy = wy - ky, dx = wx - kx;
                float v = acc[mt][nt][r];
                if (dy * dy + dx * dx <= thr2) v -= 5.0f;
                dots[(size_t)(i - m_off) * N2 + j] = f2bf(v);
            }
        }
    }
}

// ---------- per-row top-256 hinge sum ----------
// Sum of top-256 relu(x - 0.2) = sum_{x>t} relu(x-0.2) + (256 - cnt(>t)) * relu(t-0.2),
// t = 256th largest (found by bisection; exact under ties).
__global__ __launch_bounds__(256)
void select_kernel(const ushort* __restrict__ dots, float* __restrict__ out) {
    const int row = blockIdx.x;
    const int t = threadIdx.x;
    const int lane = t & 63, wave = t >> 6;
    const uint4* rp4 = (const uint4*)(dots + (size_t)row * N2);  // 8 bf16 per uint4

    float v[32];
    #pragma unroll
    for (int k = 0; k < 4; k++) {
        uint4 q = rp4[k * 256 + t];
        v[k * 8 + 0] = bf2f(q.x & 0xFFFFu); v[k * 8 + 1] = bf2f(q.x >> 16);
        v[k * 8 + 2] = bf2f(q.y & 0xFFFFu); v[k * 8 + 3] = bf2f(q.y >> 16);
        v[k * 8 + 4] = bf2f(q.z & 0xFFFFu); v[k * 8 + 5] = bf2f(q.z >> 16);
        v[k * 8 + 6] = bf2f(q.w & 0xFFFFu); v[k * 8 + 7] = bf2f(q.w >> 16);
    }

    __shared__ int s_icnt[4];
    __shared__ int s_tot;
    float lo = -300.0f, hi = 300.0f;
    for (int it = 0; it < 36; it++) {
        float mid = 0.5f * (lo + hi);
        int c = 0;
        #pragma unroll
        for (int k = 0; k < 32; k++) c += (v[k] > mid) ? 1 : 0;
        #pragma unroll
        for (int off = 32; off >= 1; off >>= 1) c += __shfl_down(c, off);
        if (lane == 0) s_icnt[wave] = c;
        __syncthreads();
        if (t == 0) s_tot = s_icnt[0] + s_icnt[1] + s_icnt[2] + s_icnt[3];
        __syncthreads();
        int total = s_tot;
        if (total >= 256) lo = mid; else hi = mid;
    }
    float tf = hi;   // cnt(> tf) <= 255; tf within ~1 ulp above 256th-largest

    float s = 0.0f; int cgt = 0;
    #pragma unroll
    for (int k = 0; k < 32; k++) {
        if (v[k] > tf) { s += fmaxf(v[k] - 0.2f, 0.0f); cgt++; }
    }
    #pragma unroll
    for (int off = 32; off >= 1; off >>= 1) {
        s += __shfl_down(s, off);
        cgt += __shfl_down(cgt, off);
    }
    __shared__ float s_s[4];
    __shared__ int s_c[4];
    if (lane == 0) { s_s[wave] = s; s_c[wave] = cgt; }
    __syncthreads();
    if (t == 0) {
        float st = s_s[0] + s_s[1] + s_s[2] + s_s[3];
        int ct = s_c[0] + s_c[1] + s_c[2] + s_c[3];
        float S = st + (float)(256 - ct) * fmaxf(tf - 0.2f, 0.0f);
        atomicAdd(out, S * INV_DENOM);
    }
}

extern "C" void kernel_launch(void* const* d_in, const int* in_sizes, int n_in,
                              void* d_out, int out_size, void* d_ws, size_t ws_size,
                              hipStream_t stream) {
    const float* wkp1  = (const float*)d_in[1];
    const float* kp2   = (const float*)d_in[2];
    const float* kp1d  = (const float*)d_in[3];
    const float* kp2d  = (const float*)d_in[4];
    const float* desc2 = (const float*)d_in[5];
    float* out = (float*)d_out;

    ushort* Abf = (ushort*)d_ws;                 // 2 MB
    ushort* Bbf = Abf + (size_t)N1 * CDIM;       // 2 MB
    ushort* dots = Bbf + (size_t)N2 * CDIM;      // remainder: desc_dot chunks (bf16)

    size_t desc_bytes = (size_t)(N1 + N2) * CDIM * sizeof(ushort);
    size_t avail = (ws_size > desc_bytes) ? (ws_size - desc_bytes) : 0;
    long rows_chunk = (long)(avail / ((size_t)N2 * sizeof(ushort)));
    rows_chunk = (rows_chunk / 128) * 128;
    if (rows_chunk > N1) rows_chunk = N1;
    if (rows_chunk < 128) rows_chunk = 128;      // requires ws >= ~6 MB

    hipMemsetAsync(d_out, 0, sizeof(float), stream);

    int n4 = N1 * CDIM / 4;
    cvt_kernel<<<(n4 + 255) / 256, 256, 0, stream>>>(kp1d, Abf, n4);
    cvt_kernel<<<(n4 + 255) / 256, 256, 0, stream>>>(kp2d, Bbf, n4);

    pos_kernel<<<N1, 128, 0, stream>>>(wkp1, kp1d, desc2, out);

    for (int r0 = 0; r0 < N1; r0 += (int)rows_chunk) {
        int rows = (int)((N1 - r0 < rows_chunk) ? (N1 - r0) : rows_chunk);
        dim3 grid(N2 / 128, rows / 128);
        gemm_kernel<<<grid, 256, 0, stream>>>(Abf, Bbf, wkp1, kp2, dots, r0);
        select_kernel<<<rows, 256, 0, stream>>>(dots, out);
    }
}

// Round 2
// 426.042 us; speedup vs baseline: 1.0421x; 1.0421x over previous
//
#include <hip/hip_runtime.h>
#include <hip/hip_bf16.h>

#define N1 8192
#define N2 8192
#define CDIM 128
#define HC 60
#define WC 80
#define HIMG 480
#define WIMG 640
#define INV_DENOM (1.0f / (8192.0f * 256.0f))

using bf16x8 = __attribute__((ext_vector_type(8))) short;
using f32x4  = __attribute__((ext_vector_type(4))) float;

__device__ __forceinline__ ushort f2bf(float f) {
    union { float f; unsigned u; } x; x.f = f;
    unsigned u = x.u;
    unsigned r = (u + 0x7FFFu + ((u >> 16) & 1u)) >> 16;
    return (ushort)r;
}
__device__ __forceinline__ float bf2f(unsigned bits) {
    union { unsigned u; float f; } x; x.u = bits << 16; return x.f;
}

// ---------- fp32 -> bf16 convert (vectorized) ----------
__global__ void cvt_kernel(const float* __restrict__ in, ushort* __restrict__ out, int n4) {
    int i = blockIdx.x * blockDim.x + threadIdx.x;
    if (i < n4) {
        float4 v = ((const float4*)in)[i];
        ushort4 o;
        o.x = f2bf(v.x); o.y = f2bf(v.y); o.z = f2bf(v.z); o.w = f2bf(v.w);
        ((ushort4*)out)[i] = o;
    }
}

// ---------- positive term ----------
__global__ void pos_kernel(const float* __restrict__ wkp1,
                           const float* __restrict__ kp1d,
                           const float* __restrict__ desc2,
                           float* __restrict__ out) {
    const int i = blockIdx.x;
    const int c = threadIdx.x;            // 128 threads = 2 waves
    float y = wkp1[2 * i], x = wkp1[2 * i + 1];
    float py = fminf(fmaxf(y / (float)(HIMG - 1) * (float)(HC - 1), 0.0f), (float)(HC - 1));
    float px = fminf(fmaxf(x / (float)(WIMG - 1) * (float)(WC - 1), 0.0f), (float)(WC - 1));
    int y0 = min(max((int)floorf(py), 0), HC - 2);
    int x0 = min(max((int)floorf(px), 0), WC - 2);
    float wy = py - (float)y0;
    float wx = px - (float)x0;
    const float* d = desc2 + (size_t)c * (HC * WC) + y0 * WC + x0;
    float v00 = d[0], v01 = d[1], v10 = d[WC], v11 = d[WC + 1];
    float v = v00 * (1.0f - wy) * (1.0f - wx) + v01 * (1.0f - wy) * wx
            + v10 * wy * (1.0f - wx) + v11 * wy * wx;
    float a = kp1d[(size_t)i * CDIM + c];
    float s2 = v * v, sav = a * v;
    #pragma unroll
    for (int off = 32; off >= 1; off >>= 1) {
        s2  += __shfl_down(s2, off);
        sav += __shfl_down(sav, off);
    }
    __shared__ float p2[2], pav[2];
    int wave = threadIdx.x >> 6, lane = threadIdx.x & 63;
    if (lane == 0) { p2[wave] = s2; pav[wave] = sav; }
    __syncthreads();
    if (threadIdx.x == 0) {
        float nrm = sqrtf(p2[0] + p2[1]);
        float pd = (pav[0] + pav[1]) / fmaxf(nrm, 1e-12f);
        float l = fmaxf(1.0f - pd, 0.0f) * (256.0f / 3.0f);
        atomicAdd(out, l * INV_DENOM);
    }
}

// ---------- masked GEMM -> bf16 dots ----------
__global__ __launch_bounds__(256, 2)
void gemm_kernel(const ushort* __restrict__ A, const ushort* __restrict__ B,
                 const float* __restrict__ wkp1, const float* __restrict__ kp2,
                 ushort* __restrict__ dots, int m_off) {
    const int n0 = blockIdx.x * 128;
    const int m0 = m_off + blockIdx.y * 128;
    const int lane = threadIdx.x & 63;
    const int wave = threadIdx.x >> 6;
    const int wm = wave >> 1, wn = wave & 1;
    const int lrow = lane & 15, quad = lane >> 4;

    f32x4 acc[4][4];
    #pragma unroll
    for (int i = 0; i < 4; i++)
        #pragma unroll
        for (int j = 0; j < 4; j++) acc[i][j] = (f32x4){0.f, 0.f, 0.f, 0.f};

    const int mbase = m0 + wm * 64 + lrow;
    const int nbase = n0 + wn * 64 + lrow;
    #pragma unroll
    for (int kit = 0; kit < 4; kit++) {
        const int kk = kit * 32 + quad * 8;
        bf16x8 af[4], bfr[4];
        #pragma unroll
        for (int t = 0; t < 4; t++) {
            af[t]  = *(const bf16x8*)(A + (size_t)(mbase + t * 16) * CDIM + kk);
            bfr[t] = *(const bf16x8*)(B + (size_t)(nbase + t * 16) * CDIM + kk);
        }
        #pragma unroll
        for (int mt = 0; mt < 4; mt++)
            #pragma unroll
            for (int nt = 0; nt < 4; nt++)
                acc[mt][nt] = __builtin_amdgcn_mfma_f32_16x16x32_bf16(
                    af[mt], bfr[nt], acc[mt][nt], 0, 0, 0);
    }

    const float thr = 2.0f * sqrtf(32.0f) + 0.1f;
    const float thr2 = thr * thr;
    #pragma unroll
    for (int nt = 0; nt < 4; nt++) {
        int j = n0 + wn * 64 + nt * 16 + lrow;       // C/D: col = lane&15
        float ky = kp2[2 * j], kx = kp2[2 * j + 1];
        #pragma unroll
        for (int mt = 0; mt < 4; mt++) {
            #pragma unroll
            for (int r = 0; r < 4; r++) {
                int i = m0 + wm * 64 + mt * 16 + quad * 4 + r;  // row = (lane>>4)*4 + reg
                float wy = wkp1[2 * i], wx = wkp1[2 * i + 1];
                float dy = wy - ky, dx = wx - kx;
                float v = acc[mt][nt][r];
                if (dy * dy + dx * dx <= thr2) v -= 5.0f;
                dots[(size_t)(i - m_off) * N2 + j] = f2bf(v);
            }
        }
    }
}

// ---------- per-row top-256 hinge sum (integer-key bisection) ----------
// Monotone key: k = b ^ (b&0x8000 ? 0xFFFF : 0x8000) maps bf16 bits -> u16
// with float ordering. 16-step integer bisection finds kt = key of the
// 256th-largest (exact, attained). Then
//   S = sum_{k > kt} relu(v - 0.2) + (256 - cnt(>kt)) * relu(vt - 0.2)
// which is exact under ties.
__global__ __launch_bounds__(256)
void select_kernel(const ushort* __restrict__ dots, float* __restrict__ out) {
    const int row = blockIdx.x;
    const int t = threadIdx.x;
    const int lane = t & 63, wave = t >> 6;
    const uint4* rp4 = (const uint4*)(dots + (size_t)row * N2);  // 8 bf16 per uint4

    // Load 32 bf16, convert to monotone u16 keys held in 32 scalar VGPRs.
    unsigned k[32];
    #pragma unroll
    for (int q = 0; q < 4; q++) {
        uint4 w = rp4[q * 256 + t];
        unsigned wd[4] = {w.x, w.y, w.z, w.w};
        #pragma unroll
        for (int j = 0; j < 4; j++) {
            unsigned x = wd[j];
            // per-halfword: b ^ 0x8000, plus extra ^0x7FFF when sign bit set
            unsigned kk = x ^ 0x80008000u ^ (((x >> 15) & 0x00010001u) * 0x7FFFu);
            k[q * 8 + 2 * j]     = kk & 0xFFFFu;
            k[q * 8 + 2 * j + 1] = kk >> 16;
        }
    }

    __shared__ int s_cnt[4];
    int lo = -1, hi = 65535;   // invariant: cnt(>lo) >= 256, cnt(>hi) <= 255
    #pragma unroll 1
    for (int it = 0; it < 16; it++) {
        unsigned mid = (unsigned)((lo + hi) >> 1);
        int c = 0;
        #pragma unroll
        for (int i = 0; i < 32; i++) c += (k[i] > mid) ? 1 : 0;
        #pragma unroll
        for (int off = 32; off >= 1; off >>= 1) c += __shfl_down(c, off);
        if (lane == 0) s_cnt[wave] = c;
        __syncthreads();
        int total = s_cnt[0] + s_cnt[1] + s_cnt[2] + s_cnt[3];
        __syncthreads();
        if (total >= 256) lo = (int)mid; else hi = (int)mid;
    }
    const unsigned kt = (unsigned)hi;           // key of 256th-largest (attained)
    unsigned bt = kt ^ ((kt & 0x8000u) ? 0x8000u : 0xFFFFu);
    const float vt = bf2f(bt);

    float s = 0.0f; int cgt = 0;
    #pragma unroll
    for (int i = 0; i < 32; i++) {
        if (k[i] > kt) {
            unsigned b = k[i] ^ ((k[i] & 0x8000u) ? 0x8000u : 0xFFFFu);
            s += fmaxf(bf2f(b) - 0.2f, 0.0f);
            cgt++;
        }
    }
    #pragma unroll
    for (int off = 32; off >= 1; off >>= 1) {
        s += __shfl_down(s, off);
        cgt += __shfl_down(cgt, off);
    }
    __shared__ float s_s[4];
    __shared__ int s_c[4];
    if (lane == 0) { s_s[wave] = s; s_c[wave] = cgt; }
    __syncthreads();
    if (t == 0) {
        float st = s_s[0] + s_s[1] + s_s[2] + s_s[3];
        int ct = s_c[0] + s_c[1] + s_c[2] + s_c[3];
        float S = st + (float)(256 - ct) * fmaxf(vt - 0.2f, 0.0f);
        atomicAdd(out, S * INV_DENOM);
    }
}

extern "C" void kernel_launch(void* const* d_in, const int* in_sizes, int n_in,
                              void* d_out, int out_size, void* d_ws, size_t ws_size,
                              hipStream_t stream) {
    const float* wkp1  = (const float*)d_in[1];
    const float* kp2   = (const float*)d_in[2];
    const float* kp1d  = (const float*)d_in[3];
    const float* kp2d  = (const float*)d_in[4];
    const float* desc2 = (const float*)d_in[5];
    float* out = (float*)d_out;

    ushort* Abf = (ushort*)d_ws;                 // 2 MB
    ushort* Bbf = Abf + (size_t)N1 * CDIM;       // 2 MB
    ushort* dots = Bbf + (size_t)N2 * CDIM;      // remainder: desc_dot chunks (bf16)

    size_t desc_bytes = (size_t)(N1 + N2) * CDIM * sizeof(ushort);
    size_t avail = (ws_size > desc_bytes) ? (ws_size - desc_bytes) : 0;
    long rows_chunk = (long)(avail / ((size_t)N2 * sizeof(ushort)));
    rows_chunk = (rows_chunk / 128) * 128;
    if (rows_chunk > N1) rows_chunk = N1;
    if (rows_chunk < 128) rows_chunk = 128;      // requires ws >= ~6 MB

    hipMemsetAsync(d_out, 0, sizeof(float), stream);

    int n4 = N1 * CDIM / 4;
    cvt_kernel<<<(n4 + 255) / 256, 256, 0, stream>>>(kp1d, Abf, n4);
    cvt_kernel<<<(n4 + 255) / 256, 256, 0, stream>>>(kp2d, Bbf, n4);

    pos_kernel<<<N1, 128, 0, stream>>>(wkp1, kp1d, desc2, out);

    for (int r0 = 0; r0 < N1; r0 += (int)rows_chunk) {
        int rows = (int)((N1 - r0 < rows_chunk) ? (N1 - r0) : rows_chunk);
        dim3 grid(N2 / 128, rows / 128);
        gemm_kernel<<<grid, 256, 0, stream>>>(Abf, Bbf, wkp1, kp2, dots, r0);
        select_kernel<<<rows, 256, 0, stream>>>(dots, out);
    }
}

// Round 3
// 417.045 us; speedup vs baseline: 1.0646x; 1.0216x over previous
//
#include <hip/hip_runtime.h>
#include <hip/hip_bf16.h>

#define N1 8192
#define N2 8192
#define CDIM 128
#define HC 60
#define WC 80
#define HIMG 480
#define WIMG 640
#define INV_DENOM (1.0f / (8192.0f * 256.0f))

using bf16x8 = __attribute__((ext_vector_type(8))) short;
using f32x4  = __attribute__((ext_vector_type(4))) float;
using u32x32 = __attribute__((ext_vector_type(32))) unsigned;

__device__ __forceinline__ ushort f2bf(float f) {
    union { float f; unsigned u; } x; x.f = f;
    unsigned u = x.u;
    unsigned r = (u + 0x7FFFu + ((u >> 16) & 1u)) >> 16;
    return (ushort)r;
}
__device__ __forceinline__ float bf2f(unsigned bits) {
    union { unsigned u; float f; } x; x.u = bits << 16; return x.f;
}

// ---------- fp32 -> bf16 convert (vectorized) ----------
__global__ void cvt_kernel(const float* __restrict__ in, ushort* __restrict__ out, int n4) {
    int i = blockIdx.x * blockDim.x + threadIdx.x;
    if (i < n4) {
        float4 v = ((const float4*)in)[i];
        ushort4 o;
        o.x = f2bf(v.x); o.y = f2bf(v.y); o.z = f2bf(v.z); o.w = f2bf(v.w);
        ((ushort4*)out)[i] = o;
    }
}

// ---------- positive term ----------
__global__ void pos_kernel(const float* __restrict__ wkp1,
                           const float* __restrict__ kp1d,
                           const float* __restrict__ desc2,
                           float* __restrict__ out) {
    const int i = blockIdx.x;
    const int c = threadIdx.x;            // 128 threads = 2 waves
    float y = wkp1[2 * i], x = wkp1[2 * i + 1];
    float py = fminf(fmaxf(y / (float)(HIMG - 1) * (float)(HC - 1), 0.0f), (float)(HC - 1));
    float px = fminf(fmaxf(x / (float)(WIMG - 1) * (float)(WC - 1), 0.0f), (float)(WC - 1));
    int y0 = min(max((int)floorf(py), 0), HC - 2);
    int x0 = min(max((int)floorf(px), 0), WC - 2);
    float wy = py - (float)y0;
    float wx = px - (float)x0;
    const float* d = desc2 + (size_t)c * (HC * WC) + y0 * WC + x0;
    float v00 = d[0], v01 = d[1], v10 = d[WC], v11 = d[WC + 1];
    float v = v00 * (1.0f - wy) * (1.0f - wx) + v01 * (1.0f - wy) * wx
            + v10 * wy * (1.0f - wx) + v11 * wy * wx;
    float a = kp1d[(size_t)i * CDIM + c];
    float s2 = v * v, sav = a * v;
    #pragma unroll
    for (int off = 32; off >= 1; off >>= 1) {
        s2  += __shfl_down(s2, off);
        sav += __shfl_down(sav, off);
    }
    __shared__ float p2[2], pav[2];
    int wave = threadIdx.x >> 6, lane = threadIdx.x & 63;
    if (lane == 0) { p2[wave] = s2; pav[wave] = sav; }
    __syncthreads();
    if (threadIdx.x == 0) {
        float nrm = sqrtf(p2[0] + p2[1]);
        float pd = (pav[0] + pav[1]) / fmaxf(nrm, 1e-12f);
        float l = fmaxf(1.0f - pd, 0.0f) * (256.0f / 3.0f);
        atomicAdd(out, l * INV_DENOM);
    }
}

// ---------- masked GEMM -> bf16 dots ----------
__global__ __launch_bounds__(256, 2)
void gemm_kernel(const ushort* __restrict__ A, const ushort* __restrict__ B,
                 const float* __restrict__ wkp1, const float* __restrict__ kp2,
                 ushort* __restrict__ dots, int m_off) {
    const int n0 = blockIdx.x * 128;
    const int m0 = m_off + blockIdx.y * 128;
    const int lane = threadIdx.x & 63;
    const int wave = threadIdx.x >> 6;
    const int wm = wave >> 1, wn = wave & 1;
    const int lrow = lane & 15, quad = lane >> 4;

    f32x4 acc[4][4];
    #pragma unroll
    for (int i = 0; i < 4; i++)
        #pragma unroll
        for (int j = 0; j < 4; j++) acc[i][j] = (f32x4){0.f, 0.f, 0.f, 0.f};

    const int mbase = m0 + wm * 64 + lrow;
    const int nbase = n0 + wn * 64 + lrow;
    #pragma unroll
    for (int kit = 0; kit < 4; kit++) {
        const int kk = kit * 32 + quad * 8;
        bf16x8 af[4], bfr[4];
        #pragma unroll
        for (int t = 0; t < 4; t++) {
            af[t]  = *(const bf16x8*)(A + (size_t)(mbase + t * 16) * CDIM + kk);
            bfr[t] = *(const bf16x8*)(B + (size_t)(nbase + t * 16) * CDIM + kk);
        }
        #pragma unroll
        for (int mt = 0; mt < 4; mt++)
            #pragma unroll
            for (int nt = 0; nt < 4; nt++)
                acc[mt][nt] = __builtin_amdgcn_mfma_f32_16x16x32_bf16(
                    af[mt], bfr[nt], acc[mt][nt], 0, 0, 0);
    }

    const float thr = 2.0f * sqrtf(32.0f) + 0.1f;
    const float thr2 = thr * thr;
    #pragma unroll
    for (int nt = 0; nt < 4; nt++) {
        int j = n0 + wn * 64 + nt * 16 + lrow;       // C/D: col = lane&15
        float ky = kp2[2 * j], kx = kp2[2 * j + 1];
        #pragma unroll
        for (int mt = 0; mt < 4; mt++) {
            #pragma unroll
            for (int r = 0; r < 4; r++) {
                int i = m0 + wm * 64 + mt * 16 + quad * 4 + r;  // row = (lane>>4)*4 + reg
                float wy = wkp1[2 * i], wx = wkp1[2 * i + 1];
                float dy = wy - ky, dx = wx - kx;
                float v = acc[mt][nt][r];
                if (dy * dy + dx * dx <= thr2) v -= 5.0f;
                dots[(size_t)(i - m_off) * N2 + j] = f2bf(v);
            }
        }
    }
}

// ---------- per-row top-256 hinge sum (integer-key bisection, reg-resident) ----------
// Keys live in an ext_vector (SSA value -> guaranteed VGPRs, no alloca).
// Per-wave counts via __popcll(__ballot(pred)): v_cmp is 1 VALU op; popcount
// + accumulate ride the scalar unit. Cross-wave combine double-buffered in LDS.
__global__ __launch_bounds__(256)
void select_kernel(const ushort* __restrict__ dots, float* __restrict__ out) {
    const int row = blockIdx.x;
    const int t = threadIdx.x;
    const int lane = t & 63, wave = t >> 6;
    const uint4* rp4 = (const uint4*)(dots + (size_t)row * N2);  // 8 bf16 per uint4

    u32x32 k;
    #pragma unroll
    for (int q = 0; q < 4; q++) {
        uint4 w = rp4[q * 256 + t];
        unsigned kk;
        kk = w.x ^ 0x80008000u ^ (((w.x >> 15) & 0x00010001u) * 0x7FFFu);
        k[q * 8 + 0] = kk & 0xFFFFu; k[q * 8 + 1] = kk >> 16;
        kk = w.y ^ 0x80008000u ^ (((w.y >> 15) & 0x00010001u) * 0x7FFFu);
        k[q * 8 + 2] = kk & 0xFFFFu; k[q * 8 + 3] = kk >> 16;
        kk = w.z ^ 0x80008000u ^ (((w.z >> 15) & 0x00010001u) * 0x7FFFu);
        k[q * 8 + 4] = kk & 0xFFFFu; k[q * 8 + 5] = kk >> 16;
        kk = w.w ^ 0x80008000u ^ (((w.w >> 15) & 0x00010001u) * 0x7FFFu);
        k[q * 8 + 6] = kk & 0xFFFFu; k[q * 8 + 7] = kk >> 16;
    }

    __shared__ int s_cnt[2][4];
    int lo = -1, hi = 65535;   // invariant: cnt(>lo) >= 256, cnt(>hi) <= 255
    #pragma unroll 1
    for (int it = 0; it < 16; it++) {
        unsigned mid = (unsigned)((lo + hi) >> 1);
        int c = 0;
        #pragma unroll
        for (int i = 0; i < 32; i++)
            c += (int)__popcll(__ballot(k[i] > mid));   // wave-uniform total
        if (lane == 0) s_cnt[it & 1][wave] = c;
        __syncthreads();   // double buffer: next iter writes the other slot
        int total = s_cnt[it & 1][0] + s_cnt[it & 1][1]
                  + s_cnt[it & 1][2] + s_cnt[it & 1][3];
        if (total >= 256) lo = (int)mid; else hi = (int)mid;
    }
    const unsigned kt = (unsigned)hi;           // key of 256th-largest (attained)
    unsigned bt = kt ^ ((kt & 0x8000u) ? 0x8000u : 0xFFFFu);
    const float vt = bf2f(bt);

    float s = 0.0f; int cgt = 0;
    #pragma unroll
    for (int i = 0; i < 32; i++) {
        cgt += (int)__popcll(__ballot(k[i] > kt));      // wave-uniform
        if (k[i] > kt) {
            unsigned b = k[i] ^ ((k[i] & 0x8000u) ? 0x8000u : 0xFFFFu);
            s += fmaxf(bf2f(b) - 0.2f, 0.0f);
        }
    }
    #pragma unroll
    for (int off = 32; off >= 1; off >>= 1) s += __shfl_down(s, off);
    __shared__ float s_s[4];
    __shared__ int s_c[4];
    if (lane == 0) { s_s[wave] = s; s_c[wave] = cgt; }
    __syncthreads();
    if (t == 0) {
        float st = s_s[0] + s_s[1] + s_s[2] + s_s[3];
        int ct = s_c[0] + s_c[1] + s_c[2] + s_c[3];
        float S = st + (float)(256 - ct) * fmaxf(vt - 0.2f, 0.0f);
        atomicAdd(out, S * INV_DENOM);
    }
}

extern "C" void kernel_launch(void* const* d_in, const int* in_sizes, int n_in,
                              void* d_out, int out_size, void* d_ws, size_t ws_size,
                              hipStream_t stream) {
    const float* wkp1  = (const float*)d_in[1];
    const float* kp2   = (const float*)d_in[2];
    const float* kp1d  = (const float*)d_in[3];
    const float* kp2d  = (const float*)d_in[4];
    const float* desc2 = (const float*)d_in[5];
    float* out = (float*)d_out;

    ushort* Abf = (ushort*)d_ws;                 // 2 MB
    ushort* Bbf = Abf + (size_t)N1 * CDIM;       // 2 MB
    ushort* dots = Bbf + (size_t)N2 * CDIM;      // remainder: desc_dot chunks (bf16)

    size_t desc_bytes = (size_t)(N1 + N2) * CDIM * sizeof(ushort);
    size_t avail = (ws_size > desc_bytes) ? (ws_size - desc_bytes) : 0;
    long rows_chunk = (long)(avail / ((size_t)N2 * sizeof(ushort)));
    rows_chunk = (rows_chunk / 128) * 128;
    if (rows_chunk > N1) rows_chunk = N1;
    if (rows_chunk < 128) rows_chunk = 128;      // requires ws >= ~6 MB

    hipMemsetAsync(d_out, 0, sizeof(float), stream);

    int n4 = N1 * CDIM / 4;
    cvt_kernel<<<(n4 + 255) / 256, 256, 0, stream>>>(kp1d, Abf, n4);
    cvt_kernel<<<(n4 + 255) / 256, 256, 0, stream>>>(kp2d, Bbf, n4);

    pos_kernel<<<N1, 128, 0, stream>>>(wkp1, kp1d, desc2, out);

    for (int r0 = 0; r0 < N1; r0 += (int)rows_chunk) {
        int rows = (int)((N1 - r0 < rows_chunk) ? (N1 - r0) : rows_chunk);
        dim3 grid(N2 / 128, rows / 128);
        gemm_kernel<<<grid, 256, 0, stream>>>(Abf, Bbf, wkp1, kp2, dots, r0);
        select_kernel<<<rows, 256, 0, stream>>>(dots, out);
    }
}